// Round 3
// baseline (2586.226 us; speedup 1.0000x reference)
//
#include <hip/hip_runtime.h>
#include <cstdint>

#define K_CODES 8192
#define D_DIM   512
#define N_VEC   32768          // 16*2048
#define DECAY   0.99f
#define EPS_VQ  1e-5f
#define COMMIT  0.25f
#define MARGIN  0.25f          // stage-1 dist error std ~0.01 -> 12 sigma safety

typedef _Float16 half_t;
typedef _Float16 half8 __attribute__((ext_vector_type(8)));
typedef _Float16 half4 __attribute__((ext_vector_type(4)));
typedef float    f32x4 __attribute__((ext_vector_type(4)));
typedef unsigned long long u64;

// async global->LDS DMA, 16B per lane; LDS dest must be linear in lane order
#define GL2L(g, l)                                                              \
    __builtin_amdgcn_global_load_lds(                                           \
        (const __attribute__((address_space(1))) unsigned int*)(g),             \
        (__attribute__((address_space(3))) unsigned int*)(l), 16, 0, 0)

__device__ __forceinline__ unsigned ordf(float f) {
    unsigned u = __float_as_uint(f);
    return (u & 0x80000000u) ? ~u : (u | 0x80000000u);
}
__device__ __forceinline__ float unordf(unsigned u) {
    u = (u & 0x80000000u) ? (u & 0x7FFFFFFFu) : ~u;
    return __uint_as_float(u);
}

// ---------------- output layout (float32, concatenated in return order) ---
// [0] loss | [1..16777217) z_q | [16777217..16809985) codes |
// [16809985..21004289) new_weight | [21004289..21012481) new_cs |
// [21012481..25206785) new_ema_w
//
// d_out scratch lifetimes:
//   A_hi f16 [out+4 ..)          32MB  (z_q region; z_q written last)
//   B_hi f16 [out+8388612 ..)     8MB  (z_q region)
//   partials [out+16809988 ..)   32MB  (new_weight/cs/ema_w region; dead
//                                       before those are memset/written)

// ---------------- K0: fp32 -> f16 cast ------------------------------------
__global__ __launch_bounds__(256)
void conv_half_kernel(const float* __restrict__ x, half_t* __restrict__ out) {
    int i = blockIdx.x * 256 + threadIdx.x;
    float4 v = ((const float4*)x)[i];
    half4 h = { (_Float16)v.x, (_Float16)v.y, (_Float16)v.z, (_Float16)v.w };
    *(half4*)(out + (size_t)i * 4) = h;
}

// ---------------- K1: wsq[k] = sum_d w[k][d]^2 (fp32) ---------------------
__global__ __launch_bounds__(256)
void wsq_kernel(const float* __restrict__ w, float* __restrict__ wsq) {
    int wave = threadIdx.x >> 6, lane = threadIdx.x & 63;
    int row  = blockIdx.x * 4 + wave;
    const float4* p = (const float4*)(w + (size_t)row * D_DIM);
    float4 a = p[lane], b = p[lane + 64];
    float s = a.x*a.x + a.y*a.y + a.z*a.z + a.w*a.w
            + b.x*b.x + b.y*b.y + b.z*b.z + b.w*b.w;
    #pragma unroll
    for (int off = 32; off; off >>= 1) s += __shfl_down(s, off);
    if (lane == 0) wsq[row] = s;
}

// ---------------- K2: single-pass f16 MFMA dist + top-2 -------------------
__global__ __launch_bounds__(256)
void dist1_kernel(const half_t* __restrict__ A, const half_t* __restrict__ B,
                  const float* __restrict__ wsq, uint4* __restrict__ partial) {
    __shared__ __align__(16) half_t As[128 * 64];
    __shared__ __align__(16) half_t Bs[128 * 64];

    const int k0 = blockIdx.x * 128;      // codes
    const int n0 = blockIdx.y * 128;      // z rows
    const int t    = threadIdx.x;
    const int lane = t & 63;
    const int wave = t >> 6;
    const int wm = (wave >> 1) * 64;
    const int wn = (wave & 1) * 64;
    const int l15 = lane & 15;
    const int q   = lane >> 4;

    f32x4 acc[4][4];
    #pragma unroll
    for (int mi = 0; mi < 4; ++mi)
        #pragma unroll
        for (int ni = 0; ni < 4; ++ni) acc[mi][ni] = (f32x4)0.0f;

    for (int c = 0; c < 8; ++c) {
        const int koff = c * 64;
        #pragma unroll
        for (int it = 0; it < 4; ++it) {
            int idx  = t + 256 * it;            // 16B chunk id, lane-linear
            int row  = idx >> 3;
            int col8 = (idx & 7) ^ (row & 7);   // XOR-swizzled global column
            GL2L(A + (size_t)(n0 + row) * D_DIM + koff + col8 * 8, As + idx * 8);
            GL2L(B + (size_t)(k0 + row) * D_DIM + koff + col8 * 8, Bs + idx * 8);
        }
        __syncthreads();
        #pragma unroll
        for (int kk = 0; kk < 2; ++kk) {
            half8 af[4], bf[4];
            const int cpos = ((kk * 4 + q) ^ (l15 & 7)) * 8;   // de-swizzle
            #pragma unroll
            for (int mi = 0; mi < 4; ++mi)
                af[mi] = *(const half8*)&As[(wm + mi * 16 + l15) * 64 + cpos];
            #pragma unroll
            for (int ni = 0; ni < 4; ++ni)
                bf[ni] = *(const half8*)&Bs[(wn + ni * 16 + l15) * 64 + cpos];
            #pragma unroll
            for (int mi = 0; mi < 4; ++mi)
                #pragma unroll
                for (int ni = 0; ni < 4; ++ni)
                    acc[mi][ni] = __builtin_amdgcn_mfma_f32_16x16x32_f16(
                        af[mi], bf[ni], acc[mi][ni], 0, 0, 0);
        }
        __syncthreads();
    }

    // epilogue: top-2 per row over this block's 128 cols; C/D layout
    // col=lane&15, row=q*4+r. LDS (As) reused for cross-wave-half merge.
    u64* sm = (u64*)As;
    #pragma unroll
    for (int mi = 0; mi < 4; ++mi) {
        #pragma unroll
        for (int r = 0; r < 4; ++r) {
            u64 k1 = ~0ull, k2 = ~0ull;
            #pragma unroll
            for (int ni = 0; ni < 4; ++ni) {
                int col = k0 + wn + ni * 16 + l15;
                float d = wsq[col] - 2.0f * acc[mi][ni][r];
                u64 key = ((u64)ordf(d) << 32) | (unsigned)col;
                if (key < k1) { k2 = k1; k1 = key; }
                else if (key < k2) k2 = key;
            }
            #pragma unroll
            for (int m = 1; m <= 8; m <<= 1) {   // merge top-2 across 16 lanes
                u64 o1 = __shfl_xor(k1, m);
                u64 o2 = __shfl_xor(k2, m);
                u64 lo = k1 < o1 ? k1 : o1;
                u64 hi = k1 < o1 ? o1 : k1;
                u64 m2 = k2 < o2 ? k2 : o2;
                k1 = lo;
                k2 = m2 < hi ? m2 : hi;
            }
            int gl = wm + mi * 16 + q * 4 + r;   // 0..127 (per wave-half pair)
            if (wn == 64 && l15 == 0) { sm[2*gl] = k1; sm[2*gl + 1] = k2; }
            __syncthreads();
            if (wn == 0 && l15 == 0) {
                u64 o1 = sm[2*gl], o2 = sm[2*gl + 1];
                u64 lo = k1 < o1 ? k1 : o1;
                u64 hi = k1 < o1 ? o1 : k1;
                u64 m2 = k2 < o2 ? k2 : o2;
                m2 = m2 < hi ? m2 : hi;
                partial[(size_t)blockIdx.x * N_VEC + n0 + gl] =
                    make_uint4((unsigned)lo, (unsigned)(lo >> 32),
                               (unsigned)(m2 >> 32), 0u);
            }
            __syncthreads();
        }
    }
}

// ---------------- K3: merge 64 partials/row, flag ambiguous rows ----------
__global__ __launch_bounds__(256)
void reduce_top2_kernel(const uint4* __restrict__ partial,
                        int* __restrict__ codes_i, float* __restrict__ codes_f,
                        int* __restrict__ cnt, int* __restrict__ list) {
    int row = blockIdx.x * 256 + threadIdx.x;
    u64 k1 = ~0ull, k2 = ~0ull;
    unsigned vm2 = 0xFFFFFFFFu;
    for (int kb = 0; kb < 64; ++kb) {
        uint4 e = partial[(size_t)kb * N_VEC + row];
        u64 k = ((u64)e.y << 32) | e.x;
        if (k < k1) { k2 = k1; k1 = k; }
        else if (k < k2) k2 = k;
        vm2 = min(vm2, e.z);
    }
    unsigned so = min((unsigned)(k2 >> 32), vm2);
    float bv = unordf((unsigned)(k1 >> 32));
    float sv = unordf(so);
    int code = (int)(k1 & 0xFFFFFFFFu);
    codes_i[row] = code;
    codes_f[row] = (float)code;
    if (sv - bv < MARGIN) { int p = atomicAdd(cnt, 1); list[p] = row; }
}

// ---------------- K4: exact fp32 re-rank of flagged rows ------------------
#define RT_PAD 516   // 512+4: breaks 16-way LDS bank conflict
__global__ __launch_bounds__(256)
void refine_pass_kernel(const float* __restrict__ z, const float* __restrict__ w,
                        const float* __restrict__ wsq,
                        const int* __restrict__ cnt, const int* __restrict__ list,
                        u64* __restrict__ exact_best) {
    __shared__ float Ws[32 * RT_PAD];   // 32 codes x 512 fp32 (padded)
    const int t = threadIdx.x;
    const int c0 = blockIdx.x * 32;
    #pragma unroll
    for (int i = 0; i < 16; ++i) {
        int fid = t + 256 * i;
        int c = fid >> 7, d4 = fid & 127;
        float4 v = ((const float4*)w)[(size_t)(c0 + c) * 128 + d4];
        *(float4*)&Ws[c * RT_PAD + d4 * 4] = v;
    }
    __syncthreads();
    const int n = *cnt;
    const int ct = t >> 3, sub = t & 7, lane = t & 63;
    for (int ii = 0; ii < n; ++ii) {
        int row = list[ii];
        const float4* zr = (const float4*)(z + (size_t)row * D_DIM);
        float dot = 0.0f;
        #pragma unroll
        for (int j = 0; j < 16; ++j) {
            float4 zv = zr[sub * 16 + j];
            float4 wv = *(const float4*)&Ws[ct * RT_PAD + sub * 64 + j * 4];
            dot += wv.x*zv.x + wv.y*zv.y + wv.z*zv.z + wv.w*zv.w;
        }
        dot += __shfl_xor(dot, 1);
        dot += __shfl_xor(dot, 2);
        dot += __shfl_xor(dot, 4);
        u64 key = ~0ull;
        if (sub == 0) {
            float dv = wsq[c0 + ct] - 2.0f * dot;
            key = ((u64)ordf(dv) << 32) | (unsigned)(c0 + ct);
        }
        #pragma unroll
        for (int m = 8; m <= 32; m <<= 1) {
            u64 o = __shfl_xor(key, m);
            key = o < key ? o : key;
        }
        if (lane == 0) atomicMin(exact_best + row, key);
    }
}

__global__ __launch_bounds__(256)
void refine_fix_kernel(const int* __restrict__ cnt, const int* __restrict__ list,
                       const u64* __restrict__ exact_best,
                       int* __restrict__ codes_i, float* __restrict__ codes_f) {
    int n = *cnt;
    for (int i = blockIdx.x * 256 + threadIdx.x; i < n; i += 64 * 256) {
        int row = list[i];
        int code = (int)(exact_best[row] & 0xFFFFFFFFu);
        codes_i[row] = code;
        codes_f[row] = (float)code;
    }
}

// ---------------- K5: counts + dw scatter ---------------------------------
__global__ __launch_bounds__(256)
void scatter_kernel(const int* __restrict__ codes_i, const float* __restrict__ z,
                    float* __restrict__ cnt_acc, float* __restrict__ dw_acc) {
    int row = blockIdx.x * 8 + (threadIdx.x >> 5);
    int c   = threadIdx.x & 31;
    int code = codes_i[row];
    if (c == 0) atomicAdd(&cnt_acc[code], 1.0f);
    const float* zr = z + (size_t)row * D_DIM;
    float* dr = dw_acc + (size_t)code * D_DIM;
    #pragma unroll
    for (int d = c; d < D_DIM; d += 32) atomicAdd(&dr[d], zr[d]);
}

// ---------------- K6: new_cs (in-place) + nsum ----------------------------
__global__ __launch_bounds__(256)
void cs_kernel(const float* __restrict__ ema_cs, float* __restrict__ cs_out,
               float* __restrict__ nsum) {
    __shared__ float wsum[4];
    int i = blockIdx.x * 256 + threadIdx.x;
    float v = ema_cs[i] * DECAY + (1.0f - DECAY) * cs_out[i];
    cs_out[i] = v;
    float s = v;
    #pragma unroll
    for (int off = 32; off; off >>= 1) s += __shfl_down(s, off);
    int lane = threadIdx.x & 63, wid = threadIdx.x >> 6;
    if (lane == 0) wsum[wid] = s;
    __syncthreads();
    if (threadIdx.x == 0)
        atomicAdd(nsum, wsum[0] + wsum[1] + wsum[2] + wsum[3]);
}

// ---------------- K7: new_ema_w (in-place) + new_weight -------------------
__global__ __launch_bounds__(256)
void weight_kernel(const float* __restrict__ ema_w, const float* __restrict__ cs,
                   const float* __restrict__ nsum_p,
                   float* __restrict__ emaw_out, float* __restrict__ w_out) {
    int i = blockIdx.x * 256 + threadIdx.x;
    float dw = emaw_out[i];
    float ne = ema_w[i] * DECAY + (1.0f - DECAY) * dw;
    emaw_out[i] = ne;
    int k = i >> 9;
    float n = *nsum_p;
    float csize = (cs[k] + EPS_VQ) / (n + (float)K_CODES * EPS_VQ) * n;
    w_out[i] = ne / csize;
}

// ---------------- K8: z_q gather + loss -----------------------------------
__global__ __launch_bounds__(256)
void gather_loss_kernel(const float* __restrict__ z, const int* __restrict__ codes,
                        const float* __restrict__ w, float* __restrict__ zq,
                        float* __restrict__ loss_acc) {
    __shared__ float wsum[4];
    int row  = blockIdx.x * 4 + (threadIdx.x >> 6);
    int lane = threadIdx.x & 63;
    int code = codes[row];
    const float* zr = z + (size_t)row * D_DIM;
    const float* wr = w + (size_t)code * D_DIM;
    float s = 0.0f;
    #pragma unroll
    for (int d = lane; d < D_DIM; d += 64) {
        float qv = wr[d];
        float diff = qv - zr[d];
        s += diff * diff;
        zq[(size_t)row * D_DIM + d] = qv;
    }
    #pragma unroll
    for (int off = 32; off; off >>= 1) s += __shfl_down(s, off);
    int wid = threadIdx.x >> 6;
    if (lane == 0) wsum[wid] = s;
    __syncthreads();
    if (threadIdx.x == 0)
        atomicAdd(loss_acc, wsum[0] + wsum[1] + wsum[2] + wsum[3]);
}

__global__ void finalize_kernel(const float* __restrict__ loss_acc,
                                float* __restrict__ out0) {
    *out0 = COMMIT * (*loss_acc) / 16777216.0f;
}

// ---------------- launch --------------------------------------------------
extern "C" void kernel_launch(void* const* d_in, const int* in_sizes, int n_in,
                              void* d_out, int out_size, void* d_ws, size_t ws_size,
                              hipStream_t stream) {
    const float* z      = (const float*)d_in[0];
    const float* weight = (const float*)d_in[1];
    const float* ema_cs = (const float*)d_in[2];
    const float* ema_w  = (const float*)d_in[3];

    float* out       = (float*)d_out;
    float* out_loss  = out;
    float* out_zq    = out + 1;
    float* out_codes = out + 16777217;
    float* out_w     = out + 16809985;
    float* out_cs    = out + 21004289;
    float* out_emaw  = out + 21012481;

    // f16 operands in z_q region (z_q written last); partials in tail region
    half_t* A_hi = (half_t*)(out + 4);
    half_t* B_hi = (half_t*)(out + 8388612);
    uint4*  partial = (uint4*)(out + 16809988);   // 16B-aligned, 32MB

    char* ws = (char*)d_ws;
    float* wsq      = (float*)ws;                 // 32KB
    int*   codes_i  = (int*)(ws + 32768);         // 128KB
    int*   cnt      = (int*)(ws + 163840);
    float* nsum     = (float*)(ws + 163844);
    float* loss_acc = (float*)(ws + 163848);
    int*   list     = (int*)(ws + 163856);        // 128KB
    u64*   exact    = (u64*)(ws + 294928);        // 256KB

    hipMemsetAsync(cnt, 0, 16, stream);                     // cnt+nsum+loss
    hipMemsetAsync(exact, 0xFF, N_VEC * 8, stream);

    conv_half_kernel<<<N_VEC * D_DIM / 1024, 256, 0, stream>>>(z, A_hi);
    conv_half_kernel<<<K_CODES * D_DIM / 1024, 256, 0, stream>>>(weight, B_hi);
    wsq_kernel<<<K_CODES / 4, 256, 0, stream>>>(weight, wsq);

    dim3 g2(K_CODES / 128, N_VEC / 128);                    // 64 x 256
    dist1_kernel<<<g2, 256, 0, stream>>>(A_hi, B_hi, wsq, partial);

    reduce_top2_kernel<<<N_VEC / 256, 256, 0, stream>>>(partial, codes_i,
                                                        out_codes, cnt, list);

    // partials dead -> accumulators may now be zeroed
    hipMemsetAsync(out_cs, 0, 8192 * 4, stream);
    hipMemsetAsync(out_emaw, 0, (size_t)4194304 * 4, stream);

    refine_pass_kernel<<<K_CODES / 32, 256, 0, stream>>>(z, weight, wsq,
                                                         cnt, list, exact);
    refine_fix_kernel<<<64, 256, 0, stream>>>(cnt, list, exact,
                                              codes_i, out_codes);

    scatter_kernel<<<N_VEC / 8, 256, 0, stream>>>(codes_i, z, out_cs, out_emaw);
    cs_kernel<<<K_CODES / 256, 256, 0, stream>>>(ema_cs, out_cs, nsum);
    weight_kernel<<<4194304 / 256, 256, 0, stream>>>(ema_w, out_cs, nsum,
                                                     out_emaw, out_w);
    gather_loss_kernel<<<N_VEC / 4, 256, 0, stream>>>(z, codes_i, out_w,
                                                      out_zq, loss_acc);
    finalize_kernel<<<1, 1, 0, stream>>>(loss_acc, out_loss);
}

// Round 4
// 1113.425 us; speedup vs baseline: 2.3228x; 2.3228x over previous
//
#include <hip/hip_runtime.h>
#include <cstdint>

#define K_CODES 8192
#define D_DIM   512
#define N_VEC   32768          // 16*2048
#define DECAY   0.99f
#define EPS_VQ  1e-5f
#define COMMIT  0.25f
#define MARGIN  0.25f          // stage-1 f16 dist error std ~0.03 -> 8 sigma

typedef _Float16 half_t;
typedef _Float16 half8 __attribute__((ext_vector_type(8)));
typedef _Float16 half4 __attribute__((ext_vector_type(4)));
typedef float    f32x4 __attribute__((ext_vector_type(4)));
typedef unsigned long long u64;

// async global->LDS DMA, 16B per lane; LDS dest must be linear in lane order
#define GL2L(g, l)                                                              \
    __builtin_amdgcn_global_load_lds(                                           \
        (const __attribute__((address_space(1))) unsigned int*)(g),             \
        (__attribute__((address_space(3))) unsigned int*)(l), 16, 0, 0)

__device__ __forceinline__ unsigned ordf(float f) {
    unsigned u = __float_as_uint(f);
    return (u & 0x80000000u) ? ~u : (u | 0x80000000u);
}
__device__ __forceinline__ float unordf(unsigned u) {
    u = (u & 0x80000000u) ? (u & 0x7FFFFFFFu) : ~u;
    return __uint_as_float(u);
}

// ---------------- output layout (float32, concatenated in return order) ---
// [0] loss | [1..16777217) z_q | [16777217..16809985) codes |
// [16809985..21004289) new_weight | [21004289..21012481) new_cs |
// [21012481..25206785) new_ema_w
//
// d_out scratch lifetimes:
//   A_hi f16 [out+4 ..)          32MB  (z_q region; z_q written last)
//   B_hi f16 [out+8388612 ..)     8MB  (z_q region)
//   partials [out+16809988 ..)   32MB  (new_weight/cs/ema_w region; dead
//                                       before those are memset/written)

// ---------------- K0: fp32 -> f16 cast ------------------------------------
__global__ __launch_bounds__(256)
void conv_half_kernel(const float* __restrict__ x, half_t* __restrict__ out) {
    int i = blockIdx.x * 256 + threadIdx.x;
    float4 v = ((const float4*)x)[i];
    half4 h = { (_Float16)v.x, (_Float16)v.y, (_Float16)v.z, (_Float16)v.w };
    *(half4*)(out + (size_t)i * 4) = h;
}

// ---------------- K1: wsq[k] = sum_d w[k][d]^2 (fp32) ---------------------
__global__ __launch_bounds__(256)
void wsq_kernel(const float* __restrict__ w, float* __restrict__ wsq) {
    int wave = threadIdx.x >> 6, lane = threadIdx.x & 63;
    int row  = blockIdx.x * 4 + wave;
    const float4* p = (const float4*)(w + (size_t)row * D_DIM);
    float4 a = p[lane], b = p[lane + 64];
    float s = a.x*a.x + a.y*a.y + a.z*a.z + a.w*a.w
            + b.x*b.x + b.y*b.y + b.z*b.z + b.w*b.w;
    #pragma unroll
    for (int off = 32; off; off >>= 1) s += __shfl_down(s, off);
    if (lane == 0) wsq[row] = s;
}

// ---------------- K2: single-pass f16 MFMA dist + top-2 -------------------
__global__ __launch_bounds__(256)
void dist1_kernel(const half_t* __restrict__ A, const half_t* __restrict__ B,
                  const float* __restrict__ wsq, uint4* __restrict__ partial) {
    __shared__ __align__(16) half_t As[128 * 64];
    __shared__ __align__(16) half_t Bs[128 * 64];

    const int k0 = blockIdx.x * 128;      // codes
    const int n0 = blockIdx.y * 128;      // z rows
    const int t    = threadIdx.x;
    const int lane = t & 63;
    const int wave = t >> 6;
    const int wm = (wave >> 1) * 64;
    const int wn = (wave & 1) * 64;
    const int l15 = lane & 15;
    const int q   = lane >> 4;

    f32x4 acc[4][4];
    #pragma unroll
    for (int mi = 0; mi < 4; ++mi)
        #pragma unroll
        for (int ni = 0; ni < 4; ++ni) acc[mi][ni] = (f32x4)0.0f;

    for (int c = 0; c < 8; ++c) {
        const int koff = c * 64;
        #pragma unroll
        for (int it = 0; it < 4; ++it) {
            int idx  = t + 256 * it;            // 16B chunk id, lane-linear
            int row  = idx >> 3;
            int col8 = (idx & 7) ^ (row & 7);   // XOR-swizzled global column
            GL2L(A + (size_t)(n0 + row) * D_DIM + koff + col8 * 8, As + idx * 8);
            GL2L(B + (size_t)(k0 + row) * D_DIM + koff + col8 * 8, Bs + idx * 8);
        }
        __syncthreads();
        #pragma unroll
        for (int kk = 0; kk < 2; ++kk) {
            half8 af[4], bf[4];
            const int cpos = ((kk * 4 + q) ^ (l15 & 7)) * 8;   // de-swizzle
            #pragma unroll
            for (int mi = 0; mi < 4; ++mi)
                af[mi] = *(const half8*)&As[(wm + mi * 16 + l15) * 64 + cpos];
            #pragma unroll
            for (int ni = 0; ni < 4; ++ni)
                bf[ni] = *(const half8*)&Bs[(wn + ni * 16 + l15) * 64 + cpos];
            #pragma unroll
            for (int mi = 0; mi < 4; ++mi)
                #pragma unroll
                for (int ni = 0; ni < 4; ++ni)
                    acc[mi][ni] = __builtin_amdgcn_mfma_f32_16x16x32_f16(
                        af[mi], bf[ni], acc[mi][ni], 0, 0, 0);
        }
        __syncthreads();
    }

    // epilogue v2: each wave computes top-2 for its 64 rows x 64-col half,
    // stashes in LDS; ONE barrier; threads t<128 merge halves + store.
    u64* sm = (u64*)As;                     // 2 halves x 128 rows x 2 u64 = 4KB
    #pragma unroll
    for (int mi = 0; mi < 4; ++mi) {
        #pragma unroll
        for (int r = 0; r < 4; ++r) {
            u64 k1 = ~0ull, k2 = ~0ull;
            #pragma unroll
            for (int ni = 0; ni < 4; ++ni) {
                int col = k0 + wn + ni * 16 + l15;
                float d = wsq[col] - 2.0f * acc[mi][ni][r];
                u64 key = ((u64)ordf(d) << 32) | (unsigned)col;
                if (key < k1) { k2 = k1; k1 = key; }
                else if (key < k2) k2 = key;
            }
            #pragma unroll
            for (int m = 1; m <= 8; m <<= 1) {   // merge top-2 across 16 lanes
                u64 o1 = __shfl_xor(k1, m);
                u64 o2 = __shfl_xor(k2, m);
                u64 lo = k1 < o1 ? k1 : o1;
                u64 hi = k1 < o1 ? o1 : k1;
                u64 m2 = k2 < o2 ? k2 : o2;
                k1 = lo;
                k2 = m2 < hi ? m2 : hi;
            }
            if (l15 == 0) {
                int rl = wm + mi * 16 + q * 4 + r;        // 0..127
                int h  = wave & 1;                         // wn half
                sm[h * 256 + 2 * rl]     = k1;
                sm[h * 256 + 2 * rl + 1] = k2;
            }
        }
    }
    __syncthreads();
    if (t < 128) {
        u64 a1 = sm[2*t], a2 = sm[2*t + 1];
        u64 b1 = sm[256 + 2*t], b2 = sm[256 + 2*t + 1];
        u64 lo = a1 < b1 ? a1 : b1;
        u64 hi = a1 < b1 ? b1 : a1;
        u64 m2 = a2 < b2 ? a2 : b2;
        m2 = m2 < hi ? m2 : hi;
        partial[(size_t)blockIdx.x * N_VEC + n0 + t] =
            make_uint4((unsigned)lo, (unsigned)(lo >> 32),
                       (unsigned)(m2 >> 32), 0u);
    }
}

// ---------------- K3: merge 64 partials/row, flag ambiguous rows ----------
__global__ __launch_bounds__(256)
void reduce_top2_kernel(const uint4* __restrict__ partial,
                        int* __restrict__ codes_i, float* __restrict__ codes_f,
                        int* __restrict__ cnt, int* __restrict__ list) {
    int row = blockIdx.x * 256 + threadIdx.x;
    u64 k1 = ~0ull, k2 = ~0ull;
    unsigned vm2 = 0xFFFFFFFFu;
    for (int kb = 0; kb < 64; ++kb) {
        uint4 e = partial[(size_t)kb * N_VEC + row];
        u64 k = ((u64)e.y << 32) | e.x;
        if (k < k1) { k2 = k1; k1 = k; }
        else if (k < k2) k2 = k;
        vm2 = min(vm2, e.z);
    }
    unsigned so = min((unsigned)(k2 >> 32), vm2);
    float bv = unordf((unsigned)(k1 >> 32));
    float sv = unordf(so);
    int code = (int)(k1 & 0xFFFFFFFFu);
    codes_i[row] = code;
    codes_f[row] = (float)code;
    if (sv - bv < MARGIN) { int p = atomicAdd(cnt, 1); list[p] = row; }
}

// ---------------- K4: exact fp32 re-rank, 64 rows x 64 codes per block ----
__global__ __launch_bounds__(256)
void refine2_kernel(const float* __restrict__ z, const float* __restrict__ w,
                    const float* __restrict__ wsq,
                    const int* __restrict__ cnt, const int* __restrict__ list,
                    u64* __restrict__ exact) {
    __shared__ float zs[64][68];      // [k][row], pad 4 -> 16B-aligned rows
    __shared__ float ws[64][68];      // [k][code]
    __shared__ int rows_s[64];
    const int n  = *cnt;
    const int c0 = blockIdx.x * 64;
    const int t  = threadIdx.x;
    const int lr = t & 63, lc = t >> 6;       // staging: row/code, k-group
    const int ty = t >> 4, tx = t & 15;       // compute: 4 rows x 4 codes

    for (int row0 = blockIdx.y * 64; row0 < n; row0 += gridDim.y * 64) {
        if (t < 64) {
            int ri = row0 + t;
            rows_s[t] = list[ri < n ? ri : n - 1];   // clamp: dup work, same result
        }
        __syncthreads();
        float acc[4][4] = {};
        const int zrow = rows_s[lr];
        for (int k0 = 0; k0 < D_DIM; k0 += 64) {
            #pragma unroll
            for (int it = 0; it < 4; ++it) {
                int kc = (lc * 4 + it) * 4;           // 0..60
                float4 v = *(const float4*)(z + (size_t)zrow * D_DIM + k0 + kc);
                zs[kc+0][lr] = v.x; zs[kc+1][lr] = v.y;
                zs[kc+2][lr] = v.z; zs[kc+3][lr] = v.w;
                float4 u = *(const float4*)(w + (size_t)(c0 + lr) * D_DIM + k0 + kc);
                ws[kc+0][lr] = u.x; ws[kc+1][lr] = u.y;
                ws[kc+2][lr] = u.z; ws[kc+3][lr] = u.w;
            }
            __syncthreads();
            #pragma unroll 8
            for (int k = 0; k < 64; ++k) {
                float4 za = *(const float4*)&zs[k][ty * 4];
                float4 wa = *(const float4*)&ws[k][tx * 4];
                float zav[4] = {za.x, za.y, za.z, za.w};
                float wav[4] = {wa.x, wa.y, wa.z, wa.w};
                #pragma unroll
                for (int i = 0; i < 4; ++i)
                    #pragma unroll
                    for (int j = 0; j < 4; ++j)
                        acc[i][j] += zav[i] * wav[j];
            }
            __syncthreads();
        }
        #pragma unroll
        for (int i = 0; i < 4; ++i) {
            u64 key = ~0ull;
            #pragma unroll
            for (int j = 0; j < 4; ++j) {
                int c = c0 + tx * 4 + j;
                float d = wsq[c] - 2.0f * acc[i][j];
                u64 k = ((u64)ordf(d) << 32) | (unsigned)c;
                if (k < key) key = k;
            }
            #pragma unroll
            for (int m = 1; m <= 8; m <<= 1) {
                u64 o = __shfl_xor(key, m);
                key = o < key ? o : key;
            }
            if (tx == 0) atomicMin(exact + rows_s[ty * 4 + i], key);
        }
        __syncthreads();   // protect rows_s/zs before next row-tile
    }
}

__global__ __launch_bounds__(256)
void refine_fix_kernel(const int* __restrict__ cnt, const int* __restrict__ list,
                       const u64* __restrict__ exact,
                       int* __restrict__ codes_i, float* __restrict__ codes_f) {
    int n = *cnt;
    for (int i = blockIdx.x * 256 + threadIdx.x; i < n; i += 64 * 256) {
        int row = list[i];
        int code = (int)(exact[row] & 0xFFFFFFFFu);
        codes_i[row] = code;
        codes_f[row] = (float)code;
    }
}

// ---------------- K5: counts + dw scatter ---------------------------------
__global__ __launch_bounds__(256)
void scatter_kernel(const int* __restrict__ codes_i, const float* __restrict__ z,
                    float* __restrict__ cnt_acc, float* __restrict__ dw_acc) {
    int row = blockIdx.x * 8 + (threadIdx.x >> 5);
    int c   = threadIdx.x & 31;
    int code = codes_i[row];
    if (c == 0) atomicAdd(&cnt_acc[code], 1.0f);
    const float* zr = z + (size_t)row * D_DIM;
    float* dr = dw_acc + (size_t)code * D_DIM;
    #pragma unroll
    for (int d = c; d < D_DIM; d += 32) atomicAdd(&dr[d], zr[d]);
}

// ---------------- K6: new_cs (in-place) + nsum ----------------------------
__global__ __launch_bounds__(256)
void cs_kernel(const float* __restrict__ ema_cs, float* __restrict__ cs_out,
               float* __restrict__ nsum) {
    __shared__ float wsum[4];
    int i = blockIdx.x * 256 + threadIdx.x;
    float v = ema_cs[i] * DECAY + (1.0f - DECAY) * cs_out[i];
    cs_out[i] = v;
    float s = v;
    #pragma unroll
    for (int off = 32; off; off >>= 1) s += __shfl_down(s, off);
    int lane = threadIdx.x & 63, wid = threadIdx.x >> 6;
    if (lane == 0) wsum[wid] = s;
    __syncthreads();
    if (threadIdx.x == 0)
        atomicAdd(nsum, wsum[0] + wsum[1] + wsum[2] + wsum[3]);
}

// ---------------- K7: new_ema_w (in-place) + new_weight -------------------
__global__ __launch_bounds__(256)
void weight_kernel(const float* __restrict__ ema_w, const float* __restrict__ cs,
                   const float* __restrict__ nsum_p,
                   float* __restrict__ emaw_out, float* __restrict__ w_out) {
    int i = blockIdx.x * 256 + threadIdx.x;
    float dw = emaw_out[i];
    float ne = ema_w[i] * DECAY + (1.0f - DECAY) * dw;
    emaw_out[i] = ne;
    int k = i >> 9;
    float n = *nsum_p;
    float csize = (cs[k] + EPS_VQ) / (n + (float)K_CODES * EPS_VQ) * n;
    w_out[i] = ne / csize;
}

// ---------------- K8: z_q gather + loss -----------------------------------
__global__ __launch_bounds__(256)
void gather_loss_kernel(const float* __restrict__ z, const int* __restrict__ codes,
                        const float* __restrict__ w, float* __restrict__ zq,
                        float* __restrict__ loss_acc) {
    __shared__ float wsum[4];
    int row  = blockIdx.x * 4 + (threadIdx.x >> 6);
    int lane = threadIdx.x & 63;
    int code = codes[row];
    const float* zr = z + (size_t)row * D_DIM;
    const float* wr = w + (size_t)code * D_DIM;
    float s = 0.0f;
    #pragma unroll
    for (int d = lane; d < D_DIM; d += 64) {
        float qv = wr[d];
        float diff = qv - zr[d];
        s += diff * diff;
        zq[(size_t)row * D_DIM + d] = qv;
    }
    #pragma unroll
    for (int off = 32; off; off >>= 1) s += __shfl_down(s, off);
    int wid = threadIdx.x >> 6;
    if (lane == 0) wsum[wid] = s;
    __syncthreads();
    if (threadIdx.x == 0)
        atomicAdd(loss_acc, wsum[0] + wsum[1] + wsum[2] + wsum[3]);
}

__global__ void finalize_kernel(const float* __restrict__ loss_acc,
                                float* __restrict__ out0) {
    *out0 = COMMIT * (*loss_acc) / 16777216.0f;
}

// ---------------- launch --------------------------------------------------
extern "C" void kernel_launch(void* const* d_in, const int* in_sizes, int n_in,
                              void* d_out, int out_size, void* d_ws, size_t ws_size,
                              hipStream_t stream) {
    const float* z      = (const float*)d_in[0];
    const float* weight = (const float*)d_in[1];
    const float* ema_cs = (const float*)d_in[2];
    const float* ema_w  = (const float*)d_in[3];

    float* out       = (float*)d_out;
    float* out_loss  = out;
    float* out_zq    = out + 1;
    float* out_codes = out + 16777217;
    float* out_w     = out + 16809985;
    float* out_cs    = out + 21004289;
    float* out_emaw  = out + 21012481;

    // f16 operands in z_q region (z_q written last); partials in tail region
    half_t* A_hi = (half_t*)(out + 4);
    half_t* B_hi = (half_t*)(out + 8388612);
    uint4*  partial = (uint4*)(out + 16809988);   // 16B-aligned, 32MB

    char* ws = (char*)d_ws;
    float* wsq      = (float*)ws;                 // 32KB
    int*   codes_i  = (int*)(ws + 32768);         // 128KB
    int*   cnt      = (int*)(ws + 163840);
    float* nsum     = (float*)(ws + 163844);
    float* loss_acc = (float*)(ws + 163848);
    int*   list     = (int*)(ws + 163856);        // 128KB
    u64*   exact    = (u64*)(ws + 294928);        // 256KB

    hipMemsetAsync(cnt, 0, 16, stream);                     // cnt+nsum+loss
    hipMemsetAsync(exact, 0xFF, N_VEC * 8, stream);

    conv_half_kernel<<<N_VEC * D_DIM / 1024, 256, 0, stream>>>(z, A_hi);
    conv_half_kernel<<<K_CODES * D_DIM / 1024, 256, 0, stream>>>(weight, B_hi);
    wsq_kernel<<<K_CODES / 4, 256, 0, stream>>>(weight, wsq);

    dim3 g2(K_CODES / 128, N_VEC / 128);                    // 64 x 256
    dist1_kernel<<<g2, 256, 0, stream>>>(A_hi, B_hi, wsq, partial);

    reduce_top2_kernel<<<N_VEC / 256, 256, 0, stream>>>(partial, codes_i,
                                                        out_codes, cnt, list);

    // partials dead -> accumulators may now be zeroed
    hipMemsetAsync(out_cs, 0, 8192 * 4, stream);
    hipMemsetAsync(out_emaw, 0, (size_t)4194304 * 4, stream);

    dim3 gr(K_CODES / 64, 64);                              // 128 x 64
    refine2_kernel<<<gr, 256, 0, stream>>>(z, weight, wsq, cnt, list, exact);
    refine_fix_kernel<<<64, 256, 0, stream>>>(cnt, list, exact,
                                              codes_i, out_codes);

    scatter_kernel<<<N_VEC / 8, 256, 0, stream>>>(codes_i, z, out_cs, out_emaw);
    cs_kernel<<<K_CODES / 256, 256, 0, stream>>>(ema_cs, out_cs, nsum);
    weight_kernel<<<4194304 / 256, 256, 0, stream>>>(ema_w, out_cs, nsum,
                                                     out_emaw, out_w);
    gather_loss_kernel<<<N_VEC / 4, 256, 0, stream>>>(z, codes_i, out_w,
                                                      out_zq, loss_acc);
    finalize_kernel<<<1, 1, 0, stream>>>(loss_acc, out_loss);
}